// Round 5
// baseline (246.132 us; speedup 1.0000x reference)
//
#include <hip/hip_runtime.h>
#include <hip/hip_bf16.h>
#include <cmath>

// Problem constants
#define BATCH   4096
#define NUNITS  1024
#define INSIZE  512
#define SIGSZ   6
#define KSIG    (NUNITS * SIGSZ)          // 6144
#define SAVED   (KSIG + NUNITS)           // 7168
#define KTOT    (INSIZE + KSIG + NUNITS)  // 7680
#define OUTW    (NUNITS * (SIGSZ + 1))    // 7168
#define NKT     (KTOT / 64)               // 120

// Workspace layout (ushort elements)
#define WS_AX 0LL
#define WS_AS 2097152LL
#define WS_AT 27262976LL
#define WS_BW 31457280LL
#define WS_BU 31981568LL
#define WS_ELEMS 39321600LL
#define WS_BYTES (WS_ELEMS * 2)           // 78,643,200

typedef __attribute__((ext_vector_type(8))) short bf16x8;
typedef __attribute__((ext_vector_type(8))) unsigned short u16x8;
typedef __attribute__((ext_vector_type(4))) float f32x4;

__device__ __forceinline__ unsigned short f2bf(float f) {
    union { float f; unsigned int u; } c; c.f = f;
    unsigned int u = c.u;
    return (unsigned short)((u + 0x7FFFu + ((u >> 16) & 1u)) >> 16);  // RNE
}

// XOR-swizzled LDS index (ushort units), 128B (64 bf16) rows.
__device__ __forceinline__ int swz(int row, int bytecol) {
    return row * 64 + (((bytecol) ^ ((row & 7) << 4)) >> 1);
}

// ---------------- prepass: fp32 -> packed bf16 in ws ----------------
__global__ __launch_bounds__(256)
void prepack(const float* __restrict__ x, const float* __restrict__ sigs,
             const float* __restrict__ states, const float* __restrict__ Ww,
             const float* __restrict__ Uw, unsigned short* __restrict__ ws)
{
    const long long stride = (long long)gridDim.x * blockDim.x;
    for (long long p = (long long)blockIdx.x * blockDim.x + threadIdx.x;
         p < 4915200LL; p += stride) {
        const float* src; unsigned short* dst; long long o;
        if (p < 262144LL)       { src = x;      dst = ws + WS_AX; o = p; }
        else if (p < 3407872LL) { src = sigs;   dst = ws + WS_AS; o = p - 262144LL; }
        else if (p < 3932160LL) { src = states; dst = ws + WS_AT; o = p - 3407872LL; }
        else if (p < 3997696LL) { src = Ww;     dst = ws + WS_BW; o = p - 3932160LL; }
        else                    { src = Uw;     dst = ws + WS_BU; o = p - 3997696LL; }
        const float4 v0 = *(const float4*)(src + o * 8);
        const float4 v1 = *(const float4*)(src + o * 8 + 4);
        u16x8 h;
        h[0] = f2bf(v0.x); h[1] = f2bf(v0.y); h[2] = f2bf(v0.z); h[3] = f2bf(v0.w);
        h[4] = f2bf(v1.x); h[5] = f2bf(v1.y); h[6] = f2bf(v1.z); h[7] = f2bf(v1.w);
        *(u16x8*)(dst + o * 8) = h;
    }
}

// ---------------- main GEMM + fused sigjoin ----------------
// 128x64 tile, BK=64, 256 threads (4 waves, 2x2 grid of 64x32 wave tiles),
// grid 512 = 2 blocks/CU. 3-deep LDS ring, counted vmcnt(6), raw s_barrier
// (one per iter, never drains the DMA queue to 0 mid-loop).
#define GLD_LDS(G, L) __builtin_amdgcn_global_load_lds(                        \
        (const __attribute__((address_space(1))) unsigned int*)(G),           \
        (__attribute__((address_space(3))) unsigned int*)(L), 16, 0, 0)

__global__ __launch_bounds__(256, 2)
void rsig_gemm(const unsigned short* __restrict__ ws,
               const float* __restrict__ sigs,
               const float* __restrict__ states,
               const float* __restrict__ Wb,
               const float* __restrict__ Ub,
               const float* __restrict__ lt,
               float* __restrict__ out)
{
    __shared__ unsigned short lA[3][128 * 64];  // 48 KB
    __shared__ unsigned short lB[3][64 * 64];   // 24 KB

    const int t = threadIdx.x;
    // XCD chunk swizzle: 512 blocks, 64/XCD, bm-major chunks (4 bm x 16 bn).
    const int p   = blockIdx.x;
    const int lid = (p & 7) * 64 + (p >> 3);
    const int bm  = lid >> 4;   // 0..31
    const int bn  = lid & 15;   // 0..15

    const int lane = t & 63;
    const int w    = t >> 6;    // 0..3
    const int wm   = w >> 1;    // 2x2 wave grid; wave tile 64x32
    const int wn   = w & 1;
    const int lr   = lane & 15;
    const int lg   = lane >> 4;

    const unsigned short* wsAx = ws + WS_AX;
    const unsigned short* wsAs = ws + WS_AS;
    const unsigned short* wsAt = ws + WS_AT;
    const unsigned short* wsBw = ws + WS_BW;
    const unsigned short* wsBu = ws + WS_BU;

    // pre-swizzled source column (elems) + row-in-group for staging
    const int sCol = 8 * ((lane & 7) ^ (lane >> 3));
    const int sRow = lane >> 3;

    f32x4 acc[4][2];
#pragma unroll
    for (int m = 0; m < 4; ++m)
#pragma unroll
        for (int n = 0; n < 2; ++n)
            acc[m][n] = (f32x4)0.f;

    // 6 gld_lds per wave per STAGE (4 A-groups + 2 B-groups)
#define STAGE(BUF, KT)                                                                  \
    {                                                                                   \
        const int kt_ = (KT);                                                           \
        const unsigned short* abase; int astr, koff;                                    \
        if (kt_ < 8)        { abase = wsAx; astr = INSIZE; koff = kt_ * 64; }           \
        else if (kt_ < 104) { abase = wsAs; astr = KSIG;   koff = kt_ * 64 - 512; }     \
        else                { abase = wsAt; astr = NUNITS; koff = kt_ * 64 - 6656; }    \
        const unsigned short* bbase; int bstr, koffb;                                   \
        if (kt_ < 8)        { bbase = wsBw; bstr = INSIZE; koffb = kt_ * 64; }          \
        else                { bbase = wsBu; bstr = SAVED;  koffb = kt_ * 64 - 512; }    \
        _Pragma("unroll")                                                               \
        for (int j = 0; j < 4; ++j) {                                                   \
            const int rg = w * 4 + j;  /* 8-row group 0..15 */                          \
            const unsigned short* g = abase                                             \
                + (size_t)(bm * 128 + rg * 8 + sRow) * astr + koff + sCol;              \
            GLD_LDS(g, &lA[BUF][rg * 512]);                                             \
        }                                                                               \
        _Pragma("unroll")                                                               \
        for (int j = 0; j < 2; ++j) {                                                   \
            const int bg = w * 2 + j;  /* 8-row group 0..7 */                           \
            const unsigned short* g = bbase                                             \
                + (size_t)(bn * 64 + bg * 8 + sRow) * bstr + koffb + sCol;              \
            GLD_LDS(g, &lB[BUF][bg * 512]);                                             \
        }                                                                               \
    }

    // Prologue: 2 tiles in flight
    STAGE(0, 0);
    STAGE(1, 1);

    int cur = 0;
    for (int kt = 0; kt < NKT; ++kt) {
        // counted wait: oldest 6 (tile kt) must land; tile kt+1's 6 stay in flight
        if (kt < NKT - 1) { asm volatile("s_waitcnt vmcnt(6)" ::: "memory"); }
        else              { asm volatile("s_waitcnt vmcnt(0)" ::: "memory"); }
        __builtin_amdgcn_s_barrier();
        __builtin_amdgcn_sched_barrier(0);

        if (kt + 2 < NKT) {
            int nb = cur + 2; if (nb >= 3) nb -= 3;
            STAGE(nb, kt + 2);   // overwrites buf[(kt-1)%3]: readers done pre-barrier
        }

#pragma unroll
        for (int ks = 0; ks < 2; ++ks) {
            bf16x8 af[4], bfr[2];
#pragma unroll
            for (int m = 0; m < 4; ++m)
                af[m] = *(const bf16x8*)&lA[cur][swz(wm * 64 + m * 16 + lr, ks * 64 + lg * 16)];
#pragma unroll
            for (int n = 0; n < 2; ++n)
                bfr[n] = *(const bf16x8*)&lB[cur][swz(wn * 32 + n * 16 + lr, ks * 64 + lg * 16)];
#pragma unroll
            for (int m = 0; m < 4; ++m)
#pragma unroll
                for (int n = 0; n < 2; ++n)
                    acc[m][n] = __builtin_amdgcn_mfma_f32_16x16x32_bf16(af[m], bfr[n], acc[m][n], 0, 0, 0);
        }

        cur = (cur == 2) ? 0 : cur + 1;
    }

    // Epilogue: raw = acc + biases; fused sigjoin (level 2), float2-vectorized
    const float tl = expf(lt[0]);
#pragma unroll
    for (int n = 0; n < 2; ++n) {
        const int u = bn * 64 + wn * 32 + n * 16 + lr;
        const float bias = Wb[u] + Ub[u];
#pragma unroll
        for (int m = 0; m < 4; ++m) {
            const int rbase = bm * 128 + wm * 64 + m * 16 + (lg << 2);
#pragma unroll
            for (int i = 0; i < 4; ++i) {
                const int b = rbase + i;
                const float raw = acc[m][n][i] + bias;
                const float ps  = states[(size_t)b * NUNITS + u];
                const float d   = raw - ps;
                const float* s  = sigs + (size_t)b * KSIG + u * 6;
                const float2 s01 = *(const float2*)(s + 0);
                const float2 s23 = *(const float2*)(s + 2);
                const float2 s45 = *(const float2*)(s + 4);
                float* o = out + (size_t)b * OUTW + u * 6;
                float2 o01, o23, o45;
                o01.x = s01.x + d;
                o01.y = s01.y + tl;
                o23.x = s23.x + 0.5f * d * d   + s01.x * d;
                o23.y = s23.y + 0.5f * d * tl  + s01.x * tl;
                o45.x = s45.x + 0.5f * tl * d  + s01.y * d;
                o45.y = s45.y + 0.5f * tl * tl + s01.y * tl;
                *(float2*)(o + 0) = o01;
                *(float2*)(o + 2) = o23;
                *(float2*)(o + 4) = o45;
                out[(size_t)b * OUTW + KSIG + u] = raw;
            }
        }
    }
#undef STAGE
}

extern "C" void kernel_launch(void* const* d_in, const int* in_sizes, int n_in,
                              void* d_out, int out_size, void* d_ws, size_t ws_size,
                              hipStream_t stream) {
    const float* x      = (const float*)d_in[0];
    const float* sigs   = (const float*)d_in[1];
    const float* states = (const float*)d_in[2];
    const float* Ww     = (const float*)d_in[3];
    const float* Wb     = (const float*)d_in[4];
    const float* Uw     = (const float*)d_in[5];
    const float* Ub     = (const float*)d_in[6];
    const float* lt     = (const float*)d_in[7];
    float* out = (float*)d_out;

    unsigned short* ws = (unsigned short*)d_ws;
    hipLaunchKernelGGL(prepack, dim3(2048), dim3(256), 0, stream,
                       x, sigs, states, Ww, Uw, ws);
    hipLaunchKernelGGL(rsig_gemm, dim3(512), dim3(256), 0, stream,
                       ws, sigs, states, Wb, Ub, lt, out);
}

// Round 6
// 208.754 us; speedup vs baseline: 1.1791x; 1.1791x over previous
//
#include <hip/hip_runtime.h>
#include <hip/hip_bf16.h>
#include <cmath>

// Problem constants
#define BATCH   4096
#define NUNITS  1024
#define INSIZE  512
#define SIGSZ   6
#define KSIG    (NUNITS * SIGSZ)          // 6144
#define SAVED   (KSIG + NUNITS)           // 7168
#define KTOT    (INSIZE + KSIG + NUNITS)  // 7680
#define OUTW    (NUNITS * (SIGSZ + 1))    // 7168
#define NKT     (KTOT / 64)               // 120

// Workspace layout (ushort elements)
#define WS_AX 0LL
#define WS_AS 2097152LL
#define WS_AT 27262976LL
#define WS_BW 31457280LL
#define WS_BU 31981568LL
#define WS_ELEMS 39321600LL
#define WS_BYTES (WS_ELEMS * 2)           // 78,643,200

typedef __attribute__((ext_vector_type(8))) short bf16x8;
typedef __attribute__((ext_vector_type(8))) unsigned short u16x8;
typedef __attribute__((ext_vector_type(4))) float f32x4;

__device__ __forceinline__ unsigned short f2bf(float f) {
    union { float f; unsigned int u; } c; c.f = f;
    unsigned int u = c.u;
    return (unsigned short)((u + 0x7FFFu + ((u >> 16) & 1u)) >> 16);  // RNE
}
__device__ __forceinline__ float bf2f(unsigned short h) {
    union { unsigned int u; float f; } c; c.u = ((unsigned int)h) << 16;
    return c.f;
}

// XOR-swizzled LDS index (ushort units), 128B (64 bf16) rows.
__device__ __forceinline__ int swz(int row, int bytecol) {
    return row * 64 + (((bytecol) ^ ((row & 7) << 4)) >> 1);
}

// ---------------- prepass: fp32 -> packed bf16 in ws ----------------
__global__ __launch_bounds__(256)
void prepack(const float* __restrict__ x, const float* __restrict__ sigs,
             const float* __restrict__ states, const float* __restrict__ Ww,
             const float* __restrict__ Uw, unsigned short* __restrict__ ws)
{
    const long long stride = (long long)gridDim.x * blockDim.x;
    for (long long p = (long long)blockIdx.x * blockDim.x + threadIdx.x;
         p < 4915200LL; p += stride) {
        const float* src; unsigned short* dst; long long o;
        if (p < 262144LL)       { src = x;      dst = ws + WS_AX; o = p; }
        else if (p < 3407872LL) { src = sigs;   dst = ws + WS_AS; o = p - 262144LL; }
        else if (p < 3932160LL) { src = states; dst = ws + WS_AT; o = p - 3407872LL; }
        else if (p < 3997696LL) { src = Ww;     dst = ws + WS_BW; o = p - 3932160LL; }
        else                    { src = Uw;     dst = ws + WS_BU; o = p - 3997696LL; }
        const float4 v0 = *(const float4*)(src + o * 8);
        const float4 v1 = *(const float4*)(src + o * 8 + 4);
        u16x8 h;
        h[0] = f2bf(v0.x); h[1] = f2bf(v0.y); h[2] = f2bf(v0.z); h[3] = f2bf(v0.w);
        h[4] = f2bf(v1.x); h[5] = f2bf(v1.y); h[6] = f2bf(v1.z); h[7] = f2bf(v1.w);
        *(u16x8*)(dst + o * 8) = h;
    }
}

// ---------------- main GEMM + fused sigjoin ----------------
// 128x128 tile, BK=64, 512 threads = 8 waves: 2(M) x 2(N) x 2(K-split).
// Each wave: 64x64 output over half the K of each tile (8 ds_read -> 16 MFMA).
// Grid 256 = 1 block/CU; bn = blockIdx&7 = XCD id under round-robin dispatch
// -> each XCD touches a single 2 MB B-slice (L2-resident).
// 3-deep LDS ring (96 KB), counted vmcnt(4), one raw s_barrier per iter.
#define GLD_LDS(G, L) __builtin_amdgcn_global_load_lds(                        \
        (const __attribute__((address_space(1))) unsigned int*)(G),           \
        (__attribute__((address_space(3))) unsigned int*)(L), 16, 0, 0)

__global__ __launch_bounds__(512, 2)
void rsig_gemm(const unsigned short* __restrict__ ws,
               const float* __restrict__ states,
               const float* __restrict__ Wb,
               const float* __restrict__ Ub,
               const float* __restrict__ lt,
               float* __restrict__ out)
{
    // per buffer (32 KB): A tile at [0, 8192), B tile at [8192, 16384) (ushorts)
    __shared__ unsigned short lds[3 * 16384];   // 96 KB

    const int t  = threadIdx.x;
    const int bn = blockIdx.x & 7;   // natural round-robin: same bn -> same XCD
    const int bm = blockIdx.x >> 3;  // 0..31

    const int lane = t & 63;
    const int w    = t >> 6;        // 0..7
    const int wm   = w >> 2;        // M half
    const int wn   = (w >> 1) & 1;  // N half
    const int wk   = w & 1;         // K slot (0: K 0..31 of tile, 1: 32..63)
    const int lr   = lane & 15;
    const int lg   = lane >> 4;

    const unsigned short* wsAx = ws + WS_AX;
    const unsigned short* wsAs = ws + WS_AS;
    const unsigned short* wsAt = ws + WS_AT;
    const unsigned short* wsBw = ws + WS_BW;
    const unsigned short* wsBu = ws + WS_BU;

    // staging: 32 groups of (8 rows x 64 cols); each wave stages 2 A + 2 B groups
    const int sRow = lane >> 3;
    const int sCol = 8 * ((lane & 7) ^ sRow);   // pre-swizzled source col (elems)
    const int g0   = w * 2;

    f32x4 acc[4][4];
#pragma unroll
    for (int m = 0; m < 4; ++m)
#pragma unroll
        for (int n = 0; n < 4; ++n)
            acc[m][n] = (f32x4)0.f;

    // 4 gld_lds per wave per STAGE (2 A-groups + 2 B-groups)
#define STAGE(BUF, KT)                                                                  \
    {                                                                                   \
        const int kt_ = (KT);                                                           \
        const unsigned short* abase; int astr, koff;                                    \
        if (kt_ < 8)        { abase = wsAx; astr = INSIZE; koff = kt_ * 64; }           \
        else if (kt_ < 104) { abase = wsAs; astr = KSIG;   koff = kt_ * 64 - 512; }     \
        else                { abase = wsAt; astr = NUNITS; koff = kt_ * 64 - 6656; }    \
        const unsigned short* bbase; int bstr, koffb;                                   \
        if (kt_ < 8)        { bbase = wsBw; bstr = INSIZE; koffb = kt_ * 64; }          \
        else                { bbase = wsBu; bstr = SAVED;  koffb = kt_ * 64 - 512; }    \
        unsigned short* base = &lds[(BUF) * 16384];                                     \
        _Pragma("unroll")                                                               \
        for (int j = 0; j < 2; ++j) {                                                   \
            const int g = g0 + j;                                                       \
            const unsigned short* ga = abase                                            \
                + (size_t)(bm * 128 + g * 8 + sRow) * astr + koff + sCol;               \
            GLD_LDS(ga, base + g * 512);                                                \
        }                                                                               \
        _Pragma("unroll")                                                               \
        for (int j = 0; j < 2; ++j) {                                                   \
            const int g = g0 + j;                                                       \
            const unsigned short* gb = bbase                                            \
                + (size_t)(bn * 128 + g * 8 + sRow) * bstr + koffb + sCol;              \
            GLD_LDS(gb, base + 8192 + g * 512);                                         \
        }                                                                               \
    }

    // Prologue: 2 tiles in flight
    STAGE(0, 0);
    STAGE(1, 1);

    int cur = 0;
    for (int kt = 0; kt < NKT; ++kt) {
        if (kt < NKT - 1) { asm volatile("s_waitcnt vmcnt(4)" ::: "memory"); }
        else              { asm volatile("s_waitcnt vmcnt(0)" ::: "memory"); }
        __builtin_amdgcn_s_barrier();
        __builtin_amdgcn_sched_barrier(0);

        if (kt + 2 < NKT) {
            int nb = cur + 2; if (nb >= 3) nb -= 3;
            STAGE(nb, kt + 2);   // overwrites buf[(kt-1)%3]: readers done pre-barrier
        }

        {
            const unsigned short* aT = &lds[cur * 16384];
            const unsigned short* bT = aT + 8192;
            bf16x8 af[4], bfr[4];
#pragma unroll
            for (int m = 0; m < 4; ++m)
                af[m] = *(const bf16x8*)&aT[swz(wm * 64 + m * 16 + lr, wk * 64 + lg * 16)];
#pragma unroll
            for (int n = 0; n < 4; ++n)
                bfr[n] = *(const bf16x8*)&bT[swz(wn * 64 + n * 16 + lr, wk * 64 + lg * 16)];
#pragma unroll
            for (int m = 0; m < 4; ++m)
#pragma unroll
                for (int n = 0; n < 4; ++n)
                    acc[m][n] = __builtin_amdgcn_mfma_f32_16x16x32_bf16(af[m], bfr[n], acc[m][n], 0, 0, 0);
        }

        cur = (cur == 2) ? 0 : cur + 1;
    }

    // ---- K-split reduction: partner waves (w ^ 1) exchange n-halves ----
    // xch uses lds bytes [0, 64K) = bufs 0,1; final tile lived in buf 2 (119%3==2).
    {
        const int give = (wk == 0) ? 2 : 0;
        float* xch  = (float*)lds;
        float* slot = xch + w * 2048;
#pragma unroll
        for (int m = 0; m < 4; ++m)
#pragma unroll
            for (int jj = 0; jj < 2; ++jj)
                *(f32x4*)(slot + ((size_t)(m * 2 + jj) * 64 + lane) * 4) = acc[m][give + jj];
        __syncthreads();
        const float* pslot = xch + (w ^ 1) * 2048;
        const int keep = 2 - give;
#pragma unroll
        for (int m = 0; m < 4; ++m)
#pragma unroll
            for (int jj = 0; jj < 2; ++jj)
                acc[m][keep + jj] += *(const f32x4*)(pslot + ((size_t)(m * 2 + jj) * 64 + lane) * 4);
    }

    // ---- Epilogue: raw = acc + biases; fused sigjoin (level 2) ----
    const float tl = expf(lt[0]);
    const int keep = (wk == 0) ? 0 : 2;
#pragma unroll
    for (int jn = 0; jn < 2; ++jn) {
        const int n = keep + jn;
        const int u = bn * 128 + wn * 64 + n * 16 + lr;
        const float bias = Wb[u] + Ub[u];
#pragma unroll
        for (int m = 0; m < 4; ++m) {
            const int rbase = bm * 128 + wm * 64 + m * 16 + (lg << 2);
#pragma unroll
            for (int i = 0; i < 4; ++i) {
                const int b = rbase + i;
                const float raw = acc[m][n][i] + bias;
                const float ps  = states[(size_t)b * NUNITS + u];
                const float d   = raw - ps;
                const unsigned short* s = wsAs + (size_t)b * KSIG + u * 6;
                const ushort2 sa = *(const ushort2*)(s + 0);
                const ushort2 sb = *(const ushort2*)(s + 2);
                const ushort2 sc = *(const ushort2*)(s + 4);
                const float s0 = bf2f(sa.x), s1 = bf2f(sa.y);
                const float s2 = bf2f(sb.x), s3 = bf2f(sb.y);
                const float s4 = bf2f(sc.x), s5 = bf2f(sc.y);
                float* o = out + (size_t)b * OUTW + u * 6;
                float2 o01, o23, o45;
                o01.x = s0 + d;
                o01.y = s1 + tl;
                o23.x = s2 + 0.5f * d * d   + s0 * d;
                o23.y = s3 + 0.5f * d * tl  + s0 * tl;
                o45.x = s4 + 0.5f * tl * d  + s1 * d;
                o45.y = s5 + 0.5f * tl * tl + s1 * tl;
                *(float2*)(o + 0) = o01;
                *(float2*)(o + 2) = o23;
                *(float2*)(o + 4) = o45;
                out[(size_t)b * OUTW + KSIG + u] = raw;
            }
        }
    }
#undef STAGE
}

extern "C" void kernel_launch(void* const* d_in, const int* in_sizes, int n_in,
                              void* d_out, int out_size, void* d_ws, size_t ws_size,
                              hipStream_t stream) {
    const float* x      = (const float*)d_in[0];
    const float* sigs   = (const float*)d_in[1];
    const float* states = (const float*)d_in[2];
    const float* Ww     = (const float*)d_in[3];
    const float* Wb     = (const float*)d_in[4];
    const float* Uw     = (const float*)d_in[5];
    const float* Ub     = (const float*)d_in[6];
    const float* lt     = (const float*)d_in[7];
    float* out = (float*)d_out;

    unsigned short* ws = (unsigned short*)d_ws;
    hipLaunchKernelGGL(prepack, dim3(2048), dim3(256), 0, stream,
                       x, sigs, states, Ww, Uw, ws);
    hipLaunchKernelGGL(rsig_gemm, dim3(256), dim3(512), 0, stream,
                       ws, states, Wb, Ub, lt, out);
}

// Round 7
// 159.295 us; speedup vs baseline: 1.5451x; 1.3105x over previous
//
#include <hip/hip_runtime.h>
#include <hip/hip_bf16.h>
#include <cmath>

// Problem constants
#define BATCH   4096
#define NUNITS  1024
#define INSIZE  512
#define SIGSZ   6
#define KSIG    (NUNITS * SIGSZ)          // 6144
#define SAVED   (KSIG + NUNITS)           // 7168
#define KTOT    (INSIZE + KSIG + NUNITS)  // 7680
#define OUTW    (NUNITS * (SIGSZ + 1))    // 7168
#define NKT     (KTOT / 64)               // 120

// Workspace layout (ushort elements)
#define WS_AX 0LL
#define WS_AS 2097152LL
#define WS_AT 27262976LL
#define WS_BW 31457280LL
#define WS_BU 31981568LL
#define WS_ELEMS 39321600LL
#define WS_BYTES (WS_ELEMS * 2)           // 78,643,200

typedef __attribute__((ext_vector_type(8))) short bf16x8;
typedef __attribute__((ext_vector_type(8))) unsigned short u16x8;
typedef __attribute__((ext_vector_type(4))) float f32x4;

__device__ __forceinline__ unsigned short f2bf(float f) {
    union { float f; unsigned int u; } c; c.f = f;
    unsigned int u = c.u;
    return (unsigned short)((u + 0x7FFFu + ((u >> 16) & 1u)) >> 16);  // RNE
}
__device__ __forceinline__ float bf2f(unsigned short h) {
    union { unsigned int u; float f; } c; c.u = ((unsigned int)h) << 16;
    return c.f;
}

// XOR-swizzled LDS index (ushort units), 128B (64 bf16) rows.
__device__ __forceinline__ int swz(int row, int bytecol) {
    return row * 64 + (((bytecol) ^ ((row & 7) << 4)) >> 1);
}

// ---------------- prepass: fp32 -> packed bf16 in ws ----------------
__global__ __launch_bounds__(256)
void prepack(const float* __restrict__ x, const float* __restrict__ sigs,
             const float* __restrict__ states, const float* __restrict__ Ww,
             const float* __restrict__ Uw, unsigned short* __restrict__ ws)
{
    const long long stride = (long long)gridDim.x * blockDim.x;
    for (long long p = (long long)blockIdx.x * blockDim.x + threadIdx.x;
         p < 4915200LL; p += stride) {
        const float* src; unsigned short* dst; long long o;
        if (p < 262144LL)       { src = x;      dst = ws + WS_AX; o = p; }
        else if (p < 3407872LL) { src = sigs;   dst = ws + WS_AS; o = p - 262144LL; }
        else if (p < 3932160LL) { src = states; dst = ws + WS_AT; o = p - 3407872LL; }
        else if (p < 3997696LL) { src = Ww;     dst = ws + WS_BW; o = p - 3932160LL; }
        else                    { src = Uw;     dst = ws + WS_BU; o = p - 3997696LL; }
        const float4 v0 = *(const float4*)(src + o * 8);
        const float4 v1 = *(const float4*)(src + o * 8 + 4);
        u16x8 h;
        h[0] = f2bf(v0.x); h[1] = f2bf(v0.y); h[2] = f2bf(v0.z); h[3] = f2bf(v0.w);
        h[4] = f2bf(v1.x); h[5] = f2bf(v1.y); h[6] = f2bf(v1.z); h[7] = f2bf(v1.w);
        *(u16x8*)(dst + o * 8) = h;
    }
}

// ---------------- main GEMM + fused sigjoin ----------------
// 128x128 tile, BK=64, 512 threads = 8 waves: 2(M) x 2(N) x 2(K-split).
// 3-deep LDS ring (96 KB), counted vmcnt(4), one raw s_barrier per iter.
// Epilogue: raw(+bias) staged into a padded 128x132 fp32 LDS tile (K-split
// merged via write-then-add), then a dense float4 store pass (full lines,
// no partial-sector RMW at HBM).
#define GLD_LDS(G, L) __builtin_amdgcn_global_load_lds(                        \
        (const __attribute__((address_space(1))) unsigned int*)(G),           \
        (__attribute__((address_space(3))) unsigned int*)(L), 16, 0, 0)

__global__ __launch_bounds__(512, 2)
void rsig_gemm(const unsigned short* __restrict__ ws,
               const float* __restrict__ states,
               const float* __restrict__ Wb,
               const float* __restrict__ Ub,
               const float* __restrict__ lt,
               float* __restrict__ out)
{
    // ring: per buffer (32 KB): A tile [0,8192), B tile [8192,16384) ushorts.
    // epilogue reuses the same LDS as a 128x132 fp32 raw tile (67.6 KB).
    __shared__ unsigned short lds[3 * 16384];   // 96 KB

    const int t  = threadIdx.x;
    const int bn = blockIdx.x & 7;   // natural round-robin: same bn -> same XCD
    const int bm = blockIdx.x >> 3;  // 0..31

    const int lane = t & 63;
    const int w    = t >> 6;        // 0..7
    const int wm   = w >> 2;        // M half
    const int wn   = (w >> 1) & 1;  // N half
    const int wk   = w & 1;         // K slot (0: K 0..31 of tile, 1: 32..63)
    const int lr   = lane & 15;
    const int lg   = lane >> 4;

    const unsigned short* wsAx = ws + WS_AX;
    const unsigned short* wsAs = ws + WS_AS;
    const unsigned short* wsAt = ws + WS_AT;
    const unsigned short* wsBw = ws + WS_BW;
    const unsigned short* wsBu = ws + WS_BU;

    // staging: 32 groups of (8 rows x 64 cols); each wave stages 2 A + 2 B groups
    const int sRow = lane >> 3;
    const int sCol = 8 * ((lane & 7) ^ sRow);   // pre-swizzled source col (elems)
    const int g0   = w * 2;

    f32x4 acc[4][4];
#pragma unroll
    for (int m = 0; m < 4; ++m)
#pragma unroll
        for (int n = 0; n < 4; ++n)
            acc[m][n] = (f32x4)0.f;

    // 4 gld_lds per wave per STAGE (2 A-groups + 2 B-groups)
#define STAGE(BUF, KT)                                                                  \
    {                                                                                   \
        const int kt_ = (KT);                                                           \
        const unsigned short* abase; int astr, koff;                                    \
        if (kt_ < 8)        { abase = wsAx; astr = INSIZE; koff = kt_ * 64; }           \
        else if (kt_ < 104) { abase = wsAs; astr = KSIG;   koff = kt_ * 64 - 512; }     \
        else                { abase = wsAt; astr = NUNITS; koff = kt_ * 64 - 6656; }    \
        const unsigned short* bbase; int bstr, koffb;                                   \
        if (kt_ < 8)        { bbase = wsBw; bstr = INSIZE; koffb = kt_ * 64; }          \
        else                { bbase = wsBu; bstr = SAVED;  koffb = kt_ * 64 - 512; }    \
        unsigned short* base = &lds[(BUF) * 16384];                                     \
        _Pragma("unroll")                                                               \
        for (int j = 0; j < 2; ++j) {                                                   \
            const int g = g0 + j;                                                       \
            const unsigned short* ga = abase                                            \
                + (size_t)(bm * 128 + g * 8 + sRow) * astr + koff + sCol;               \
            GLD_LDS(ga, base + g * 512);                                                \
        }                                                                               \
        _Pragma("unroll")                                                               \
        for (int j = 0; j < 2; ++j) {                                                   \
            const int g = g0 + j;                                                       \
            const unsigned short* gb = bbase                                            \
                + (size_t)(bn * 128 + g * 8 + sRow) * bstr + koffb + sCol;              \
            GLD_LDS(gb, base + 8192 + g * 512);                                         \
        }                                                                               \
    }

    // Prologue: 2 tiles in flight
    STAGE(0, 0);
    STAGE(1, 1);

    int cur = 0;
    for (int kt = 0; kt < NKT; ++kt) {
        if (kt < NKT - 1) { asm volatile("s_waitcnt vmcnt(4)" ::: "memory"); }
        else              { asm volatile("s_waitcnt vmcnt(0)" ::: "memory"); }
        __builtin_amdgcn_s_barrier();
        __builtin_amdgcn_sched_barrier(0);

        if (kt + 2 < NKT) {
            int nb = cur + 2; if (nb >= 3) nb -= 3;
            STAGE(nb, kt + 2);   // overwrites buf[(kt-1)%3]: readers done pre-barrier
        }

        {
            const unsigned short* aT = &lds[cur * 16384];
            const unsigned short* bT = aT + 8192;
            bf16x8 af[4], bfr[4];
#pragma unroll
            for (int m = 0; m < 4; ++m)
                af[m] = *(const bf16x8*)&aT[swz(wm * 64 + m * 16 + lr, wk * 64 + lg * 16)];
#pragma unroll
            for (int n = 0; n < 4; ++n)
                bfr[n] = *(const bf16x8*)&bT[swz(wn * 64 + n * 16 + lr, wk * 64 + lg * 16)];
#pragma unroll
            for (int m = 0; m < 4; ++m)
#pragma unroll
                for (int n = 0; n < 4; ++n)
                    acc[m][n] = __builtin_amdgcn_mfma_f32_16x16x32_bf16(af[m], bfr[n], acc[m][n], 0, 0, 0);
        }

        cur = (cur == 2) ? 0 : cur + 1;
    }

    // all waves done reading the last ring buffer before LDS reuse
    __syncthreads();

    // ---- Phase 1: raw(+bias) -> padded LDS tile; K-split merged in-place ----
    float* rawt = (float*)lds;            // 128 rows x 132 floats
    if (wk == 0) {
#pragma unroll
        for (int n = 0; n < 4; ++n) {
            const int ug = bn * 128 + wn * 64 + n * 16 + lr;
            const float bias = Wb[ug] + Ub[ug];
            const int cc = wn * 64 + n * 16 + lr;
#pragma unroll
            for (int m = 0; m < 4; ++m) {
                const int rr = wm * 64 + m * 16 + lg * 4;
#pragma unroll
                for (int i = 0; i < 4; ++i)
                    rawt[(rr + i) * 132 + cc] = acc[m][n][i] + bias;
            }
        }
    }
    __syncthreads();
    if (wk == 1) {
#pragma unroll
        for (int n = 0; n < 4; ++n) {
            const int cc = wn * 64 + n * 16 + lr;
#pragma unroll
            for (int m = 0; m < 4; ++m) {
                const int rr = wm * 64 + m * 16 + lg * 4;
#pragma unroll
                for (int i = 0; i < 4; ++i)
                    rawt[(rr + i) * 132 + cc] += acc[m][n][i];
            }
        }
    }
    __syncthreads();

    // ---- Phase 2: dense float4 store pass ----
    // 256 threads per row: c in [0,192) -> sig float4; [192,224) -> raw float4.
    const float tl = expf(lt[0]);
    const int r0 = t >> 8;      // 0..1
    const int c  = t & 255;

    for (int pass = 0; pass < 64; ++pass) {
        const int r = pass * 2 + r0;
        const long long b = (long long)bm * 128 + r;
        if (c < 192) {
            const int u  = (2 * c) / 3;
            const int cs = c % 3;
            const unsigned short* srow = wsAs + b * KSIG + bn * 768;
            const float* strow = states + b * NUNITS + bn * 128;
            const ushort4 sin = *(const ushort4*)(srow + c * 4);
            const float e0 = bf2f(sin.x), e1 = bf2f(sin.y);
            const float e2 = bf2f(sin.z), e3 = bf2f(sin.w);
            float4 o;
            if (cs == 0) {                 // cols 6u+0..3: s0,s1,s2,s3
                const float d = rawt[r * 132 + u] - strow[u];
                o.x = e0 + d;
                o.y = e1 + tl;
                o.z = e2 + d  * (0.5f * d  + e0);
                o.w = e3 + tl * (0.5f * d  + e0);
            } else if (cs == 1) {          // cols 6u+4,5, 6(u+1)+0,1
                const float d  = rawt[r * 132 + u]     - strow[u];
                const float dn = rawt[r * 132 + u + 1] - strow[u + 1];
                const float s1 = bf2f(srow[u * 6 + 1]);
                o.x = e0 + d  * (0.5f * tl + s1);
                o.y = e1 + tl * (0.5f * tl + s1);
                o.z = e2 + dn;
                o.w = e3 + tl;
            } else {                       // cols 6u+2..5: s2,s3,s4,s5
                const float d = rawt[r * 132 + u] - strow[u];
                const unsigned int sv = *(const unsigned int*)(srow + u * 6);
                const float s0 = bf2f((unsigned short)(sv & 0xffffu));
                const float s1 = bf2f((unsigned short)(sv >> 16));
                o.x = e0 + d  * (0.5f * d  + s0);
                o.y = e1 + tl * (0.5f * d  + s0);
                o.z = e2 + d  * (0.5f * tl + s1);
                o.w = e3 + tl * (0.5f * tl + s1);
            }
            *(float4*)(out + b * OUTW + bn * 768 + c * 4) = o;
        } else if (c < 224) {
            const int cc = (c - 192) * 4;
            const float4 rv = *(const float4*)&rawt[r * 132 + cc];
            *(float4*)(out + b * OUTW + KSIG + bn * 128 + cc) = rv;
        }
    }
#undef STAGE
}

extern "C" void kernel_launch(void* const* d_in, const int* in_sizes, int n_in,
                              void* d_out, int out_size, void* d_ws, size_t ws_size,
                              hipStream_t stream) {
    const float* x      = (const float*)d_in[0];
    const float* sigs   = (const float*)d_in[1];
    const float* states = (const float*)d_in[2];
    const float* Ww     = (const float*)d_in[3];
    const float* Wb     = (const float*)d_in[4];
    const float* Uw     = (const float*)d_in[5];
    const float* Ub     = (const float*)d_in[6];
    const float* lt     = (const float*)d_in[7];
    float* out = (float*)d_out;

    unsigned short* ws = (unsigned short*)d_ws;
    hipLaunchKernelGGL(prepack, dim3(2048), dim3(256), 0, stream,
                       x, sigs, states, Ww, Uw, ws);
    hipLaunchKernelGGL(rsig_gemm, dim3(256), dim3(512), 0, stream,
                       ws, states, Wb, Ub, lt, out);
}

// Round 8
// 149.849 us; speedup vs baseline: 1.6425x; 1.0630x over previous
//
#include <hip/hip_runtime.h>
#include <hip/hip_bf16.h>
#include <cmath>

// Problem constants
#define BATCH   4096
#define NUNITS  1024
#define INSIZE  512
#define SIGSZ   6
#define KSIG    (NUNITS * SIGSZ)          // 6144
#define SAVED   (KSIG + NUNITS)           // 7168
#define KTOT    (INSIZE + KSIG + NUNITS)  // 7680
#define OUTW    (NUNITS * (SIGSZ + 1))    // 7168
#define NKT     (KTOT / 64)               // 120

// Workspace layout (ushort elements)
#define WS_AX 0LL
#define WS_AS 2097152LL
#define WS_AT 27262976LL
#define WS_BW 31457280LL
#define WS_BU 31981568LL
#define WS_ELEMS 39321600LL
#define WS_BYTES (WS_ELEMS * 2)           // 78,643,200

typedef __attribute__((ext_vector_type(8))) short bf16x8;
typedef __attribute__((ext_vector_type(8))) unsigned short u16x8;
typedef __attribute__((ext_vector_type(4))) float f32x4;

__device__ __forceinline__ unsigned short f2bf(float f) {
    union { float f; unsigned int u; } c; c.f = f;
    unsigned int u = c.u;
    return (unsigned short)((u + 0x7FFFu + ((u >> 16) & 1u)) >> 16);  // RNE
}
__device__ __forceinline__ float bf2f(unsigned short h) {
    union { unsigned int u; float f; } c; c.u = ((unsigned int)h) << 16;
    return c.f;
}

// XOR-swizzled LDS index (ushort units), 128B (64 bf16) rows.
__device__ __forceinline__ int swz(int row, int bytecol) {
    return row * 64 + (((bytecol) ^ ((row & 7) << 4)) >> 1);
}

// ---------------- prepass: fp32 -> packed bf16 in ws ----------------
__global__ __launch_bounds__(256)
void prepack(const float* __restrict__ x, const float* __restrict__ sigs,
             const float* __restrict__ states, const float* __restrict__ Ww,
             const float* __restrict__ Uw, unsigned short* __restrict__ ws)
{
    const long long stride = (long long)gridDim.x * blockDim.x;
    for (long long p = (long long)blockIdx.x * blockDim.x + threadIdx.x;
         p < 4915200LL; p += stride) {
        const float* src; unsigned short* dst; long long o;
        if (p < 262144LL)       { src = x;      dst = ws + WS_AX; o = p; }
        else if (p < 3407872LL) { src = sigs;   dst = ws + WS_AS; o = p - 262144LL; }
        else if (p < 3932160LL) { src = states; dst = ws + WS_AT; o = p - 3407872LL; }
        else if (p < 3997696LL) { src = Ww;     dst = ws + WS_BW; o = p - 3932160LL; }
        else                    { src = Uw;     dst = ws + WS_BU; o = p - 3997696LL; }
        const float4 v0 = *(const float4*)(src + o * 8);
        const float4 v1 = *(const float4*)(src + o * 8 + 4);
        u16x8 h;
        h[0] = f2bf(v0.x); h[1] = f2bf(v0.y); h[2] = f2bf(v0.z); h[3] = f2bf(v0.w);
        h[4] = f2bf(v1.x); h[5] = f2bf(v1.y); h[6] = f2bf(v1.z); h[7] = f2bf(v1.w);
        *(u16x8*)(dst + o * 8) = h;
    }
}

// ---------------- main GEMM + fused sigjoin ----------------
// 128x128 tile, BK=64, 1024 threads = 16 waves: 2(M) x 4(N) x 2(K-split).
// Wave tile 64x32 per K-half (4 ds_read A + 2 ds_read B -> 8 MFMA).
// Grid 256 = 1 block/CU; bn = blockIdx&7 = XCD id (B-slice L2-resident).
// 3-deep LDS ring (96 KB), counted vmcnt(2), one raw s_barrier per iter.
// Epilogue: raw(+bias) -> padded 128x132 fp32 LDS tile (K-split merged),
// then dense float4 store pass (full lines, no RMW).
#define GLD_LDS(G, L) __builtin_amdgcn_global_load_lds(                        \
        (const __attribute__((address_space(1))) unsigned int*)(G),           \
        (__attribute__((address_space(3))) unsigned int*)(L), 16, 0, 0)

__global__ __launch_bounds__(1024, 1)
void rsig_gemm(const unsigned short* __restrict__ ws,
               const float* __restrict__ states,
               const float* __restrict__ Wb,
               const float* __restrict__ Ub,
               const float* __restrict__ lt,
               float* __restrict__ out)
{
    // ring: per buffer (32 KB): A tile [0,8192), B tile [8192,16384) ushorts.
    // epilogue reuses the same LDS as a 128x132 fp32 raw tile (67.6 KB).
    __shared__ unsigned short lds[3 * 16384];   // 96 KB

    const int t  = threadIdx.x;
    const int bn = blockIdx.x & 7;   // natural round-robin: same bn -> same XCD
    const int bm = blockIdx.x >> 3;  // 0..31

    const int lane = t & 63;
    const int w    = t >> 6;        // 0..15
    const int wm   = w >> 3;        // M half (0..1)
    const int wn   = (w >> 1) & 3;  // N quarter (0..3)
    const int wk   = w & 1;         // K slot (0: K 0..31 of tile, 1: 32..63)
    const int lr   = lane & 15;
    const int lg   = lane >> 4;

    const unsigned short* wsAx = ws + WS_AX;
    const unsigned short* wsAs = ws + WS_AS;
    const unsigned short* wsAt = ws + WS_AT;
    const unsigned short* wsBw = ws + WS_BW;
    const unsigned short* wsBu = ws + WS_BU;

    // staging: 16 A-groups + 16 B-groups of (8 rows x 64 cols); 1 A + 1 B per wave
    const int sRow = lane >> 3;
    const int sCol = 8 * ((lane & 7) ^ sRow);   // pre-swizzled source col (elems)

    f32x4 acc[4][2];
#pragma unroll
    for (int m = 0; m < 4; ++m)
#pragma unroll
        for (int n = 0; n < 2; ++n)
            acc[m][n] = (f32x4)0.f;

    // 2 gld_lds per wave per STAGE (1 A-group + 1 B-group)
#define STAGE(BUF, KT)                                                                  \
    {                                                                                   \
        const int kt_ = (KT);                                                           \
        const unsigned short* abase; int astr, koff;                                    \
        if (kt_ < 8)        { abase = wsAx; astr = INSIZE; koff = kt_ * 64; }           \
        else if (kt_ < 104) { abase = wsAs; astr = KSIG;   koff = kt_ * 64 - 512; }     \
        else                { abase = wsAt; astr = NUNITS; koff = kt_ * 64 - 6656; }    \
        const unsigned short* bbase; int bstr, koffb;                                   \
        if (kt_ < 8)        { bbase = wsBw; bstr = INSIZE; koffb = kt_ * 64; }          \
        else                { bbase = wsBu; bstr = SAVED;  koffb = kt_ * 64 - 512; }    \
        unsigned short* base = &lds[(BUF) * 16384];                                     \
        const unsigned short* ga = abase                                                \
            + (size_t)(bm * 128 + w * 8 + sRow) * astr + koff + sCol;                   \
        GLD_LDS(ga, base + w * 512);                                                    \
        const unsigned short* gb = bbase                                                \
            + (size_t)(bn * 128 + w * 8 + sRow) * bstr + koffb + sCol;                  \
        GLD_LDS(gb, base + 8192 + w * 512);                                             \
    }

    // Prologue: 2 tiles in flight (4 loads/wave outstanding)
    STAGE(0, 0);
    STAGE(1, 1);

    int cur = 0;
    for (int kt = 0; kt < NKT; ++kt) {
        if (kt < NKT - 1) { asm volatile("s_waitcnt vmcnt(2)" ::: "memory"); }
        else              { asm volatile("s_waitcnt vmcnt(0)" ::: "memory"); }
        __builtin_amdgcn_s_barrier();
        __builtin_amdgcn_sched_barrier(0);

        if (kt + 2 < NKT) {
            int nb = cur + 2; if (nb >= 3) nb -= 3;
            STAGE(nb, kt + 2);   // overwrites buf[(kt-1)%3]: readers done pre-barrier
        }

        {
            const unsigned short* aT = &lds[cur * 16384];
            const unsigned short* bT = aT + 8192;
            bf16x8 af[4], bfr[2];
#pragma unroll
            for (int m = 0; m < 4; ++m)
                af[m] = *(const bf16x8*)&aT[swz(wm * 64 + m * 16 + lr, wk * 64 + lg * 16)];
#pragma unroll
            for (int n = 0; n < 2; ++n)
                bfr[n] = *(const bf16x8*)&bT[swz(wn * 32 + n * 16 + lr, wk * 64 + lg * 16)];
#pragma unroll
            for (int m = 0; m < 4; ++m)
#pragma unroll
                for (int n = 0; n < 2; ++n)
                    acc[m][n] = __builtin_amdgcn_mfma_f32_16x16x32_bf16(af[m], bfr[n], acc[m][n], 0, 0, 0);
        }

        cur = (cur == 2) ? 0 : cur + 1;
    }

    // all waves done reading the last ring buffer before LDS reuse
    __syncthreads();

    // ---- Phase 1: raw(+bias) -> padded LDS tile; K-split merged in-place ----
    float* rawt = (float*)lds;            // 128 rows x 132 floats
    if (wk == 0) {
#pragma unroll
        for (int n = 0; n < 2; ++n) {
            const int cc = wn * 32 + n * 16 + lr;
            const int ug = bn * 128 + cc;
            const float bias = Wb[ug] + Ub[ug];
#pragma unroll
            for (int m = 0; m < 4; ++m) {
                const int rr = wm * 64 + m * 16 + lg * 4;
#pragma unroll
                for (int i = 0; i < 4; ++i)
                    rawt[(rr + i) * 132 + cc] = acc[m][n][i] + bias;
            }
        }
    }
    __syncthreads();
    if (wk == 1) {
#pragma unroll
        for (int n = 0; n < 2; ++n) {
            const int cc = wn * 32 + n * 16 + lr;
#pragma unroll
            for (int m = 0; m < 4; ++m) {
                const int rr = wm * 64 + m * 16 + lg * 4;
#pragma unroll
                for (int i = 0; i < 4; ++i)
                    rawt[(rr + i) * 132 + cc] += acc[m][n][i];
            }
        }
    }
    __syncthreads();

    // ---- Phase 2: dense float4 store pass ----
    // per row: c in [0,192) -> sig float4; [192,224) -> raw float4.
    const float tl = expf(lt[0]);
    const int r0 = t >> 8;      // 0..3
    const int c  = t & 255;

    for (int pass = 0; pass < 32; ++pass) {
        const int r = pass * 4 + r0;
        const long long b = (long long)bm * 128 + r;
        if (c < 192) {
            const int u  = (2 * c) / 3;
            const int cs = c % 3;
            const unsigned short* srow = wsAs + b * KSIG + bn * 768;
            const float* strow = states + b * NUNITS + bn * 128;
            const ushort4 sin = *(const ushort4*)(srow + c * 4);
            const float e0 = bf2f(sin.x), e1 = bf2f(sin.y);
            const float e2 = bf2f(sin.z), e3 = bf2f(sin.w);
            float4 o;
            if (cs == 0) {                 // cols 6u+0..3: s0,s1,s2,s3
                const float d = rawt[r * 132 + u] - strow[u];
                o.x = e0 + d;
                o.y = e1 + tl;
                o.z = e2 + d  * (0.5f * d  + e0);
                o.w = e3 + tl * (0.5f * d  + e0);
            } else if (cs == 1) {          // cols 6u+4,5, 6(u+1)+0,1
                const float d  = rawt[r * 132 + u]     - strow[u];
                const float dn = rawt[r * 132 + u + 1] - strow[u + 1];
                const float s1 = bf2f(srow[u * 6 + 1]);
                o.x = e0 + d  * (0.5f * tl + s1);
                o.y = e1 + tl * (0.5f * tl + s1);
                o.z = e2 + dn;
                o.w = e3 + tl;
            } else {                       // cols 6u+2..5: s2,s3,s4,s5
                const float d = rawt[r * 132 + u] - strow[u];
                const unsigned int sv = *(const unsigned int*)(srow + u * 6);
                const float s0 = bf2f((unsigned short)(sv & 0xffffu));
                const float s1 = bf2f((unsigned short)(sv >> 16));
                o.x = e0 + d  * (0.5f * d  + s0);
                o.y = e1 + tl * (0.5f * d  + s0);
                o.z = e2 + d  * (0.5f * tl + s1);
                o.w = e3 + tl * (0.5f * tl + s1);
            }
            *(float4*)(out + b * OUTW + bn * 768 + c * 4) = o;
        } else if (c < 224) {
            const int cc = (c - 192) * 4;
            const float4 rv = *(const float4*)&rawt[r * 132 + cc];
            *(float4*)(out + b * OUTW + KSIG + bn * 128 + cc) = rv;
        }
    }
#undef STAGE
}

extern "C" void kernel_launch(void* const* d_in, const int* in_sizes, int n_in,
                              void* d_out, int out_size, void* d_ws, size_t ws_size,
                              hipStream_t stream) {
    const float* x      = (const float*)d_in[0];
    const float* sigs   = (const float*)d_in[1];
    const float* states = (const float*)d_in[2];
    const float* Ww     = (const float*)d_in[3];
    const float* Wb     = (const float*)d_in[4];
    const float* Uw     = (const float*)d_in[5];
    const float* Ub     = (const float*)d_in[6];
    const float* lt     = (const float*)d_in[7];
    float* out = (float*)d_out;

    unsigned short* ws = (unsigned short*)d_ws;
    hipLaunchKernelGGL(prepack, dim3(2048), dim3(256), 0, stream,
                       x, sigs, states, Ww, Uw, ws);
    hipLaunchKernelGGL(rsig_gemm, dim3(256), dim3(1024), 0, stream,
                       ws, states, Wb, Ub, lt, out);
}